// Round 18
// baseline (575.169 us; speedup 1.0000x reference)
//
#include <hip/hip_runtime.h>
#include <hip/hip_bf16.h>
#include <stdint.h>

#define NN 10000
#define EE 50000
#define MPAD 50176  // EE padded to multiple of 128

typedef __hip_bfloat16 bf16_t;
typedef __attribute__((ext_vector_type(8))) short bf16x8;
typedef __attribute__((ext_vector_type(4))) float f32x4;
typedef char cx4 __attribute__((ext_vector_type(4)));

__device__ __forceinline__ float bf2f(unsigned short u) {
  union { unsigned int i; float f; } v; v.i = ((unsigned int)u) << 16; return v.f;
}

__device__ __forceinline__ void async_load16(const void* g, void* lds) {
  __builtin_amdgcn_global_load_lds((const __attribute__((address_space(1))) uint32_t*)g,
                                   (__attribute__((address_space(3))) uint32_t*)lds,
                                   16, 0, 0);
}

#define MFMA16(a, b, c) __builtin_amdgcn_mfma_f32_16x16x32_bf16(a, b, c, 0, 0, 0)

// C[M][N] = act(A[M][K] @ Bt[N][K]^T + bias[N]); bf16 row-major, M,N mult 128, K mult 64.
// Proven r2 structure: 944 TF, MfmaUtil 42%, 0 bank conflicts. DO NOT TOUCH without A/B.
template <bool RELU>
__global__ __launch_bounds__(256, 2)
void gemm_bt(const bf16_t* __restrict__ A, const bf16_t* __restrict__ Bt,
             const float* __restrict__ bias, bf16_t* __restrict__ C,
             int N, int K) {
  __shared__ __align__(16) bf16_t As[128 * 64];
  __shared__ __align__(16) bf16_t Bs[128 * 64];

  const int t = threadIdx.x;
  const int lane = t & 63;
  const int wave = t >> 6;
  const int nt = N >> 7;
  const int bm = blockIdx.x / nt;
  const int bn = blockIdx.x % nt;
  const size_t aRowBase = (size_t)bm << 7;
  const size_t bRowBase = (size_t)bn << 7;

  const int wrBase = (wave >> 1) << 6;
  const int wcBase = (wave & 1) << 6;
  const int lo = lane & 15;
  const int hi = lane >> 4;

  f32x4 acc[4][4] = {};

  const int stg_r = t >> 3;
  const int stg_s = t & 7;
  char* AsB = (char*)As;
  char* BsB = (char*)Bs;

  const int nkt = K >> 6;
  for (int kt = 0; kt < nkt; ++kt) {
    __syncthreads();
    #pragma unroll
    for (int it = 0; it < 4; ++it) {
      const int r = (it << 5) + stg_r;
      const int ls = (stg_s ^ (r & 7)) << 3;
      async_load16(A + (aRowBase + r) * K + (kt << 6) + ls,
                   AsB + (it << 12) + (wave << 10));
      async_load16(Bt + (bRowBase + r) * K + (kt << 6) + ls,
                   BsB + (it << 12) + (wave << 10));
    }
    __syncthreads();
    #pragma unroll
    for (int ks = 0; ks < 2; ++ks) {
      bf16x8 af[4], bfr[4];
      #pragma unroll
      for (int m = 0; m < 4; ++m) {
        const int row = wrBase + (m << 4) + lo;
        const int ps = ((ks << 2) + hi) ^ (row & 7);
        af[m] = *(const bf16x8*)(AsB + (row << 7) + (ps << 4));
      }
      #pragma unroll
      for (int n = 0; n < 4; ++n) {
        const int row = wcBase + (n << 4) + lo;
        const int ps = ((ks << 2) + hi) ^ (row & 7);
        bfr[n] = *(const bf16x8*)(BsB + (row << 7) + (ps << 4));
      }
      #pragma unroll
      for (int m = 0; m < 4; ++m)
        #pragma unroll
        for (int n = 0; n < 4; ++n)
          acc[m][n] = MFMA16(af[m], bfr[n], acc[m][n]);
    }
  }

  #pragma unroll
  for (int m = 0; m < 4; ++m) {
    #pragma unroll
    for (int n = 0; n < 4; ++n) {
      const int col = (bn << 7) + wcBase + (n << 4) + lo;
      const float bv = bias[col];
      #pragma unroll
      for (int j = 0; j < 4; ++j) {
        const int row = (bm << 7) + wrBase + (m << 4) + (hi << 2) + j;
        float v = acc[m][n][j] + bv;
        if (RELU) v = fmaxf(v, 0.0f);
        C[(size_t)row * N + col] = __float2bfloat16(v);
      }
    }
  }
}

// k3 GEMM (no bias) with int8-quantizing epilogue.
// Wq[edge][i][byte: c*4+k] stores o = k*16+c (k=0..3, c=0..15) for i-block i = 2*bn + (wave&1).
// Sq[edge][i] = rowblock max/127 (f32). Per-(row,i) max over 64 cols via 4-step lo-lane butterfly.
// r18: (256,4) -- 60 VGPR + 64 AGPR = 124 <= 128 cap (no spill, r7 rule), 32KB LDS -> 4 blocks/CU
// to hide the quantize-epilogue tail (r16 precedent: same lever, +7%).
__global__ __launch_bounds__(256, 4)
void gemm_q(const bf16_t* __restrict__ A, const bf16_t* __restrict__ Bt,
            char* __restrict__ Wq, float* __restrict__ Sq, int e0) {
  __shared__ __align__(16) bf16_t As[128 * 64];
  __shared__ __align__(16) bf16_t Bs[128 * 64];

  const int t = threadIdx.x;
  const int lane = t & 63;
  const int wave = t >> 6;
  const int bm = blockIdx.x >> 5;   // 32 col-tiles (N = 4096)
  const int bn = blockIdx.x & 31;
  const size_t aRowBase = (size_t)bm << 7;
  const size_t bRowBase = (size_t)bn << 7;

  const int wrBase = (wave >> 1) << 6;
  const int wcb = wave & 1;
  const int wcBase = wcb << 6;
  const int lo = lane & 15;
  const int hi = lane >> 4;

  f32x4 acc[4][4] = {};

  const int stg_r = t >> 3;
  const int stg_s = t & 7;
  char* AsB = (char*)As;
  char* BsB = (char*)Bs;

  for (int kt = 0; kt < 8; ++kt) {  // K = 512
    __syncthreads();
    #pragma unroll
    for (int it = 0; it < 4; ++it) {
      const int r = (it << 5) + stg_r;
      const int ls = (stg_s ^ (r & 7)) << 3;
      async_load16(A + (aRowBase + r) * 512 + (kt << 6) + ls,
                   AsB + (it << 12) + (wave << 10));
      async_load16(Bt + (bRowBase + r) * 512 + (kt << 6) + ls,
                   BsB + (it << 12) + (wave << 10));
    }
    __syncthreads();
    #pragma unroll
    for (int ks = 0; ks < 2; ++ks) {
      bf16x8 af[4], bfr[4];
      #pragma unroll
      for (int m = 0; m < 4; ++m) {
        const int row = wrBase + (m << 4) + lo;
        const int ps = ((ks << 2) + hi) ^ (row & 7);
        af[m] = *(const bf16x8*)(AsB + (row << 7) + (ps << 4));
      }
      #pragma unroll
      for (int n = 0; n < 4; ++n) {
        const int row = wcBase + (n << 4) + lo;
        const int ps = ((ks << 2) + hi) ^ (row & 7);
        bfr[n] = *(const bf16x8*)(BsB + (row << 7) + (ps << 4));
      }
      #pragma unroll
      for (int m = 0; m < 4; ++m)
        #pragma unroll
        for (int n = 0; n < 4; ++n)
          acc[m][n] = MFMA16(af[m], bfr[n], acc[m][n]);
    }
  }

  // quantizing epilogue (bias NOT included -- handled exactly via bterm in msg_q)
  const int ib = (bn << 1) + wcb;  // i block 0..63
  #pragma unroll
  for (int m = 0; m < 4; ++m) {
    #pragma unroll
    for (int j = 0; j < 4; ++j) {
      const int row = (bm << 7) + wrBase + (m << 4) + (hi << 2) + j;
      float mx = 0.0f;
      #pragma unroll
      for (int n = 0; n < 4; ++n) mx = fmaxf(mx, fabsf(acc[m][n][j]));
      mx = fmaxf(mx, __shfl_xor(mx, 1));
      mx = fmaxf(mx, __shfl_xor(mx, 2));
      mx = fmaxf(mx, __shfl_xor(mx, 4));
      mx = fmaxf(mx, __shfl_xor(mx, 8));
      const float inv = (mx > 0.0f) ? (127.0f / mx) : 0.0f;
      char4 qb;
      qb.x = (signed char)(int)rintf(acc[m][0][j] * inv);
      qb.y = (signed char)(int)rintf(acc[m][1][j] * inv);
      qb.z = (signed char)(int)rintf(acc[m][2][j] * inv);
      qb.w = (signed char)(int)rintf(acc[m][3][j] * inv);
      *(char4*)(Wq + ((size_t)(e0 + row) << 12) + (ib << 6) + (lo << 2)) = qb;
      if (lo == 0) Sq[((size_t)(e0 + row) << 6) + ib] = mx * (1.0f / 127.0f);
    }
  }
}

// per-edge matvec from int8 W-cache: msg[o] = sum_i h[src][i]*s[i]*q[i][o] + bterm[src][o].
// Lane (g = lane>>4, c = lane&15) handles i = i0+g, o = k*16+c (k=0..3) -- matches gemm_q layout.
// 8 edges/block, 2 per wave interleaved (MLP). r18: W loads non-temporal (205MB/layer
// zero-reuse stream) so h (2.5MB, randomly re-read 50k x/layer) and agg stay L2-resident.
__global__ __launch_bounds__(256)
void msg_q(const float* __restrict__ h, const char* __restrict__ Wq,
           const float* __restrict__ Sq, const float* __restrict__ bterm,
           const int* __restrict__ ei, float* __restrict__ agg, int ne) {
  const int t = threadIdx.x, lane = t & 63;
  const int base = (blockIdx.x << 3) + (t >> 6);
  const int el0 = base, el1 = base + 4;
  bool v0 = el0 < ne, v1 = el1 < ne;
  unsigned s0 = 0, d0 = 0, s1 = 0, d1 = 0;
  if (v0) { s0 = (unsigned)ei[el0]; d0 = (unsigned)ei[EE + el0];
            if (s0 >= NN || d0 >= NN) v0 = false; }
  if (v1) { s1 = (unsigned)ei[el1]; d1 = (unsigned)ei[EE + el1];
            if (s1 >= NN || d1 >= NN) v1 = false; }
  const int g = lane >> 4, c = lane & 15;
  const float hv0 = v0 ? h[s0 * 64 + lane] : 0.0f;
  const float hv1 = v1 ? h[s1 * 64 + lane] : 0.0f;
  const char* W0 = Wq + ((size_t)(v0 ? el0 : 0) << 12);
  const char* W1 = Wq + ((size_t)(v1 ? el1 : 0) << 12);
  const float* S0 = Sq + ((size_t)(v0 ? el0 : 0) << 6);
  const float* S1 = Sq + ((size_t)(v1 ? el1 : 0) << 6);
  float a0[4] = {}, a1[4] = {};
  #pragma unroll
  for (int i0 = 0; i0 < 64; i0 += 4) {
    const int i = i0 + g;
    const float hs0 = __shfl(hv0, i) * S0[i];
    const float hs1 = __shfl(hv1, i) * S1[i];
    const cx4 q0 = __builtin_nontemporal_load((const cx4*)(W0 + (i << 6) + (c << 2)));
    const cx4 q1 = __builtin_nontemporal_load((const cx4*)(W1 + (i << 6) + (c << 2)));
    a0[0] = fmaf(hs0, (float)q0[0], a0[0]);
    a0[1] = fmaf(hs0, (float)q0[1], a0[1]);
    a0[2] = fmaf(hs0, (float)q0[2], a0[2]);
    a0[3] = fmaf(hs0, (float)q0[3], a0[3]);
    a1[0] = fmaf(hs1, (float)q1[0], a1[0]);
    a1[1] = fmaf(hs1, (float)q1[1], a1[1]);
    a1[2] = fmaf(hs1, (float)q1[2], a1[2]);
    a1[3] = fmaf(hs1, (float)q1[3], a1[3]);
  }
  #pragma unroll
  for (int k = 0; k < 4; ++k) {
    a0[k] += __shfl_xor(a0[k], 16); a0[k] += __shfl_xor(a0[k], 32);
    a1[k] += __shfl_xor(a1[k], 16); a1[k] += __shfl_xor(a1[k], 32);
  }
  if (g == 0) {
    if (v0) {
      #pragma unroll
      for (int k = 0; k < 4; ++k) {
        const int o = (k << 4) + c;
        atomicAdd(agg + ((size_t)d0 << 6) + o, a0[k] + bterm[((size_t)s0 << 6) + o]);
      }
    }
    if (v1) {
      #pragma unroll
      for (int k = 0; k < 4; ++k) {
        const int o = (k << 4) + c;
        atomicAdd(agg + ((size_t)d1 << 6) + o, a1[k] + bterm[((size_t)s1 << 6) + o]);
      }
    }
  }
}

// bterm[n][o] = sum_i h[n][i] * b3[i*64+o]  (exact fp32 bias path)
__global__ __launch_bounds__(256)
void bterm_kernel(const float* __restrict__ h, const float* __restrict__ b3,
                  float* __restrict__ bt) {
  const int n = blockIdx.x * 4 + (threadIdx.x >> 6);
  if (n >= NN) return;
  const int lane = threadIdx.x & 63;
  const float hv = h[n * 64 + lane];
  float acc = 0.0f;
  #pragma unroll
  for (int i = 0; i < 64; ++i)
    acc = fmaf(__shfl(hv, i), b3[i * 64 + lane], acc);
  bt[(size_t)n * 64 + lane] = acc;
}

// wt[n*K + k] = bf16(w[k*N + n])  (transpose + cast)
__global__ void convert_t(const float* __restrict__ w, bf16_t* __restrict__ wt,
                          int K, int N) {
  int idx = blockIdx.x * 256 + threadIdx.x;
  if (idx >= K * N) return;
  int n = idx / K, k = idx - n * K;
  wt[idx] = __float2bfloat16(w[(size_t)k * N + n]);
}

__global__ void fc1_kernel(const float* __restrict__ x, const float* __restrict__ w,
                           const float* __restrict__ b, float* __restrict__ h) {
  int idx = blockIdx.x * 256 + threadIdx.x;
  if (idx >= NN * 64) return;
  int n = idx >> 6, j = idx & 63;
  h[idx] = fmaf(x[n], w[j], b[j]);
}

__global__ void deg_kernel(const int* __restrict__ ei, float* __restrict__ deg) {
  int e = blockIdx.x * 256 + threadIdx.x;
  if (e < EE) {
    unsigned d = (unsigned)ei[EE + e];
    if (d < NN) atomicAdd(&deg[d], 1.0f);
  }
}

// e1[el][0:256] = relu(attr[e0+el] @ k1_w + k1_b), zeros for rows >= ne
__global__ void k1_kernel(const float* __restrict__ attr, const float* __restrict__ w,
                          const float* __restrict__ b, bf16_t* __restrict__ e1,
                          int e0, int ne) {
  const int el = blockIdx.x;
  const int j = threadIdx.x;
  __shared__ float a[6];
  if (el < ne && j < 6) a[j] = attr[(size_t)(e0 + el) * 6 + j];
  __syncthreads();
  float v = 0.0f;
  if (el < ne) {
    v = b[j];
    #pragma unroll
    for (int i = 0; i < 6; ++i) v = fmaf(a[i], w[i * 256 + j], v);
    v = fmaxf(v, 0.0f);
  }
  e1[(size_t)el * 256 + j] = __float2bfloat16(v);
}

// h_new = relu(agg/deg + h @ root + gcn_b)
__global__ __launch_bounds__(256)
void update_kernel(const float* __restrict__ h, const float* __restrict__ agg,
                   const float* __restrict__ deg, const float* __restrict__ root,
                   const float* __restrict__ gb, float* __restrict__ hn) {
  const int n = blockIdx.x * 4 + (threadIdx.x >> 6);
  if (n >= NN) return;
  const int lane = threadIdx.x & 63;
  const float hv = h[n * 64 + lane];
  float acc = 0.0f;
  #pragma unroll
  for (int i = 0; i < 64; ++i)
    acc = fmaf(__shfl(hv, i), root[i * 64 + lane], acc);
  const float d = fmaxf(deg[n], 1.0f);
  const float v = agg[n * 64 + lane] / d + acc + gb[lane];
  hn[n * 64 + lane] = fmaxf(v, 0.0f);
}

__global__ __launch_bounds__(256)
void fc2_kernel(const float* __restrict__ h, const float* __restrict__ w,
                const float* __restrict__ b, float* __restrict__ out) {
  const int n = blockIdx.x * 4 + (threadIdx.x >> 6);
  if (n >= NN) return;
  const int lane = threadIdx.x & 63;
  float v = h[n * 64 + lane] * w[lane];
  #pragma unroll
  for (int off = 32; off > 0; off >>= 1) v += __shfl_xor(v, off);
  if (lane == 0) out[n] = v + b[0];
}

extern "C" void kernel_launch(void* const* d_in, const int* in_sizes, int n_in,
                              void* d_out, int out_size, void* d_ws, size_t ws_size,
                              hipStream_t stream) {
  const float* x     = (const float*)d_in[0];
  const int*   ei    = (const int*)d_in[1];
  const float* attr  = (const float*)d_in[2];
  const float* fc1_w = (const float*)d_in[3];
  const float* fc1_b = (const float*)d_in[4];
  const float* k1_w  = (const float*)d_in[5];
  const float* k1_b  = (const float*)d_in[6];
  const float* k2_w  = (const float*)d_in[7];
  const float* k2_b  = (const float*)d_in[8];
  const float* k3_w  = (const float*)d_in[9];
  const float* k3_b  = (const float*)d_in[10];
  const float* root  = (const float*)d_in[11];
  const float* gcn_b = (const float*)d_in[12];
  const float* fc2_w = (const float*)d_in[13];
  const float* fc2_b = (const float*)d_in[14];
  float* out = (float*)d_out;
  (void)in_sizes; (void)n_in; (void)out_size; (void)ws_size;

  char* ws = (char*)d_ws;
  size_t off = 0;
  auto take = [&](size_t bytes) -> char* {
    char* p = ws + off;
    off += (bytes + 255) & ~(size_t)255;
    return p;
  };
  // fixed buffers (~14.8 MB)
  bf16_t* k2wt  = (bf16_t*)take((size_t)512 * 256 * 2);
  bf16_t* k3wt  = (bf16_t*)take((size_t)4096 * 512 * 2);
  float*  hA    = (float*)take((size_t)NN * 64 * 4);
  float*  hB    = (float*)take((size_t)NN * 64 * 4);
  float*  agg   = (float*)take((size_t)NN * 64 * 4);
  float*  deg   = (float*)take((size_t)NN * 4);
  float*  bterm = (float*)take((size_t)NN * 64 * 4);
  // chunked fill scratch (3 chunks of 16768 edges): e1c 8.6MB + e2c 17.2MB
  const int Cc = 16768;
  bf16_t* e1c = (bf16_t*)take((size_t)Cc * 256 * 2);
  bf16_t* e2c = (bf16_t*)take((size_t)Cc * 512 * 2);
  // int8 W cache: Wq 205.5MB + Sq 12.85MB  (total ~259MB <= 256MiB ws)
  float* Sq = (float*)take((size_t)MPAD * 64 * 4);
  char*  Wq = take((size_t)MPAD * 4096);

  // weight transposes + casts
  convert_t<<<(512 * 256 + 255) / 256, 256, 0, stream>>>(k2_w, k2wt, 256, 512);
  convert_t<<<(4096 * 512 + 255) / 256, 256, 0, stream>>>(k3_w, k3wt, 512, 4096);

  // h0 = x @ fc1_w + fc1_b
  fc1_kernel<<<(NN * 64 + 255) / 256, 256, 0, stream>>>(x, fc1_w, fc1_b, hA);

  // in-degree
  hipMemsetAsync(deg, 0, NN * 4, stream);
  deg_kernel<<<(EE + 255) / 256, 256, 0, stream>>>(ei, deg);

  // fill int8 W-cache in 3 chunks: k1 -> e1c, k2 -> e2c, gemm_q -> Wq+Sq
  for (int e0 = 0; e0 < EE; e0 += Cc) {
    int ne = EE - e0; if (ne > Cc) ne = Cc;
    const int np = (ne + 127) & ~127;
    k1_kernel<<<np, 256, 0, stream>>>(attr, k1_w, k1_b, e1c, e0, ne);
    gemm_bt<true><<<(np >> 7) * 4, 256, 0, stream>>>(e1c, k2wt, k2_b, e2c, 512, 256);
    gemm_q<<<(np >> 7) * 32, 256, 0, stream>>>(e2c, k3wt, Wq, Sq, e0);
  }

  float* hc = hA;
  float* hn = hB;
  for (int l = 0; l < 3; ++l) {
    hipMemsetAsync(agg, 0, (size_t)NN * 64 * 4, stream);
    bterm_kernel<<<(NN + 3) / 4, 256, 0, stream>>>(hc, k3_b, bterm);
    msg_q<<<(EE + 7) / 8, 256, 0, stream>>>(hc, Wq, Sq, bterm, ei, agg, EE);
    update_kernel<<<(NN + 3) / 4, 256, 0, stream>>>(hc, agg, deg, root, gcn_b, hn);
    float* tmp = hc; hc = hn; hn = tmp;
  }

  fc2_kernel<<<(NN + 3) / 4, 256, 0, stream>>>(hc, fc2_w, fc2_b, out);
}

// Round 19
// 530.150 us; speedup vs baseline: 1.0849x; 1.0849x over previous
//
#include <hip/hip_runtime.h>
#include <hip/hip_bf16.h>
#include <stdint.h>

#define NN 10000
#define EE 50000
#define MPAD 50176  // EE padded to multiple of 128

typedef __hip_bfloat16 bf16_t;
typedef __attribute__((ext_vector_type(8))) short bf16x8;
typedef __attribute__((ext_vector_type(4))) float f32x4;
typedef char cx4 __attribute__((ext_vector_type(4)));

__device__ __forceinline__ float bf2f(unsigned short u) {
  union { unsigned int i; float f; } v; v.i = ((unsigned int)u) << 16; return v.f;
}

__device__ __forceinline__ void async_load16(const void* g, void* lds) {
  __builtin_amdgcn_global_load_lds((const __attribute__((address_space(1))) uint32_t*)g,
                                   (__attribute__((address_space(3))) uint32_t*)lds,
                                   16, 0, 0);
}

#define MFMA16(a, b, c) __builtin_amdgcn_mfma_f32_16x16x32_bf16(a, b, c, 0, 0, 0)

// C[M][N] = act(A[M][K] @ Bt[N][K]^T + bias[N]); bf16 row-major, M,N mult 128, K mult 64.
// Proven r2 structure: 944 TF, MfmaUtil 42%, 0 bank conflicts. DO NOT TOUCH without A/B.
template <bool RELU>
__global__ __launch_bounds__(256, 2)
void gemm_bt(const bf16_t* __restrict__ A, const bf16_t* __restrict__ Bt,
             const float* __restrict__ bias, bf16_t* __restrict__ C,
             int N, int K) {
  __shared__ __align__(16) bf16_t As[128 * 64];
  __shared__ __align__(16) bf16_t Bs[128 * 64];

  const int t = threadIdx.x;
  const int lane = t & 63;
  const int wave = t >> 6;
  const int nt = N >> 7;
  const int bm = blockIdx.x / nt;
  const int bn = blockIdx.x % nt;
  const size_t aRowBase = (size_t)bm << 7;
  const size_t bRowBase = (size_t)bn << 7;

  const int wrBase = (wave >> 1) << 6;
  const int wcBase = (wave & 1) << 6;
  const int lo = lane & 15;
  const int hi = lane >> 4;

  f32x4 acc[4][4] = {};

  const int stg_r = t >> 3;
  const int stg_s = t & 7;
  char* AsB = (char*)As;
  char* BsB = (char*)Bs;

  const int nkt = K >> 6;
  for (int kt = 0; kt < nkt; ++kt) {
    __syncthreads();
    #pragma unroll
    for (int it = 0; it < 4; ++it) {
      const int r = (it << 5) + stg_r;
      const int ls = (stg_s ^ (r & 7)) << 3;
      async_load16(A + (aRowBase + r) * K + (kt << 6) + ls,
                   AsB + (it << 12) + (wave << 10));
      async_load16(Bt + (bRowBase + r) * K + (kt << 6) + ls,
                   BsB + (it << 12) + (wave << 10));
    }
    __syncthreads();
    #pragma unroll
    for (int ks = 0; ks < 2; ++ks) {
      bf16x8 af[4], bfr[4];
      #pragma unroll
      for (int m = 0; m < 4; ++m) {
        const int row = wrBase + (m << 4) + lo;
        const int ps = ((ks << 2) + hi) ^ (row & 7);
        af[m] = *(const bf16x8*)(AsB + (row << 7) + (ps << 4));
      }
      #pragma unroll
      for (int n = 0; n < 4; ++n) {
        const int row = wcBase + (n << 4) + lo;
        const int ps = ((ks << 2) + hi) ^ (row & 7);
        bfr[n] = *(const bf16x8*)(BsB + (row << 7) + (ps << 4));
      }
      #pragma unroll
      for (int m = 0; m < 4; ++m)
        #pragma unroll
        for (int n = 0; n < 4; ++n)
          acc[m][n] = MFMA16(af[m], bfr[n], acc[m][n]);
    }
  }

  #pragma unroll
  for (int m = 0; m < 4; ++m) {
    #pragma unroll
    for (int n = 0; n < 4; ++n) {
      const int col = (bn << 7) + wcBase + (n << 4) + lo;
      const float bv = bias[col];
      #pragma unroll
      for (int j = 0; j < 4; ++j) {
        const int row = (bm << 7) + wrBase + (m << 4) + (hi << 2) + j;
        float v = acc[m][n][j] + bv;
        if (RELU) v = fmaxf(v, 0.0f);
        C[(size_t)row * N + col] = __float2bfloat16(v);
      }
    }
  }
}

// k3 GEMM (no bias) with int8-quantizing epilogue.
// Wq[edge][i][byte: c*4+k] stores o = k*16+c (k=0..3, c=0..15) for i-block i = 2*bn + (wave&1).
// Sq[edge][i] = rowblock max/127 (f32). Per-(row,i) max over 64 cols via 4-step lo-lane butterfly.
// (256,2): r18's (256,4) capped VGPR at 128 < live+temporaries -> scratch spill
// (WRITE_SIZE 84->160MB, 88->109us). Measured-good config: 60 VGPR, zero spill.
__global__ __launch_bounds__(256, 2)
void gemm_q(const bf16_t* __restrict__ A, const bf16_t* __restrict__ Bt,
            char* __restrict__ Wq, float* __restrict__ Sq, int e0) {
  __shared__ __align__(16) bf16_t As[128 * 64];
  __shared__ __align__(16) bf16_t Bs[128 * 64];

  const int t = threadIdx.x;
  const int lane = t & 63;
  const int wave = t >> 6;
  const int bm = blockIdx.x >> 5;   // 32 col-tiles (N = 4096)
  const int bn = blockIdx.x & 31;
  const size_t aRowBase = (size_t)bm << 7;
  const size_t bRowBase = (size_t)bn << 7;

  const int wrBase = (wave >> 1) << 6;
  const int wcb = wave & 1;
  const int wcBase = wcb << 6;
  const int lo = lane & 15;
  const int hi = lane >> 4;

  f32x4 acc[4][4] = {};

  const int stg_r = t >> 3;
  const int stg_s = t & 7;
  char* AsB = (char*)As;
  char* BsB = (char*)Bs;

  for (int kt = 0; kt < 8; ++kt) {  // K = 512
    __syncthreads();
    #pragma unroll
    for (int it = 0; it < 4; ++it) {
      const int r = (it << 5) + stg_r;
      const int ls = (stg_s ^ (r & 7)) << 3;
      async_load16(A + (aRowBase + r) * 512 + (kt << 6) + ls,
                   AsB + (it << 12) + (wave << 10));
      async_load16(Bt + (bRowBase + r) * 512 + (kt << 6) + ls,
                   BsB + (it << 12) + (wave << 10));
    }
    __syncthreads();
    #pragma unroll
    for (int ks = 0; ks < 2; ++ks) {
      bf16x8 af[4], bfr[4];
      #pragma unroll
      for (int m = 0; m < 4; ++m) {
        const int row = wrBase + (m << 4) + lo;
        const int ps = ((ks << 2) + hi) ^ (row & 7);
        af[m] = *(const bf16x8*)(AsB + (row << 7) + (ps << 4));
      }
      #pragma unroll
      for (int n = 0; n < 4; ++n) {
        const int row = wcBase + (n << 4) + lo;
        const int ps = ((ks << 2) + hi) ^ (row & 7);
        bfr[n] = *(const bf16x8*)(BsB + (row << 7) + (ps << 4));
      }
      #pragma unroll
      for (int m = 0; m < 4; ++m)
        #pragma unroll
        for (int n = 0; n < 4; ++n)
          acc[m][n] = MFMA16(af[m], bfr[n], acc[m][n]);
    }
  }

  // quantizing epilogue (bias NOT included -- handled exactly via bterm in msg_q)
  const int ib = (bn << 1) + wcb;  // i block 0..63
  #pragma unroll
  for (int m = 0; m < 4; ++m) {
    #pragma unroll
    for (int j = 0; j < 4; ++j) {
      const int row = (bm << 7) + wrBase + (m << 4) + (hi << 2) + j;
      float mx = 0.0f;
      #pragma unroll
      for (int n = 0; n < 4; ++n) mx = fmaxf(mx, fabsf(acc[m][n][j]));
      mx = fmaxf(mx, __shfl_xor(mx, 1));
      mx = fmaxf(mx, __shfl_xor(mx, 2));
      mx = fmaxf(mx, __shfl_xor(mx, 4));
      mx = fmaxf(mx, __shfl_xor(mx, 8));
      const float inv = (mx > 0.0f) ? (127.0f / mx) : 0.0f;
      char4 qb;
      qb.x = (signed char)(int)rintf(acc[m][0][j] * inv);
      qb.y = (signed char)(int)rintf(acc[m][1][j] * inv);
      qb.z = (signed char)(int)rintf(acc[m][2][j] * inv);
      qb.w = (signed char)(int)rintf(acc[m][3][j] * inv);
      *(char4*)(Wq + ((size_t)(e0 + row) << 12) + (ib << 6) + (lo << 2)) = qb;
      if (lo == 0) Sq[((size_t)(e0 + row) << 6) + ib] = mx * (1.0f / 127.0f);
    }
  }
}

// per-edge matvec from int8 W-cache: msg[o] = sum_i h[src][i]*s[i]*q[i][o] + bterm[src][o].
// Lane (g = lane>>4, c = lane&15) handles i = i0+g, o = k*16+c (k=0..3) -- matches gemm_q layout.
// 8 edges/block, 2 per wave interleaved (MLP). W loads non-temporal (205MB/layer
// zero-reuse stream) so h (2.5MB, randomly re-read 50k x/layer) and agg stay L2-resident.
__global__ __launch_bounds__(256)
void msg_q(const float* __restrict__ h, const char* __restrict__ Wq,
           const float* __restrict__ Sq, const float* __restrict__ bterm,
           const int* __restrict__ ei, float* __restrict__ agg, int ne) {
  const int t = threadIdx.x, lane = t & 63;
  const int base = (blockIdx.x << 3) + (t >> 6);
  const int el0 = base, el1 = base + 4;
  bool v0 = el0 < ne, v1 = el1 < ne;
  unsigned s0 = 0, d0 = 0, s1 = 0, d1 = 0;
  if (v0) { s0 = (unsigned)ei[el0]; d0 = (unsigned)ei[EE + el0];
            if (s0 >= NN || d0 >= NN) v0 = false; }
  if (v1) { s1 = (unsigned)ei[el1]; d1 = (unsigned)ei[EE + el1];
            if (s1 >= NN || d1 >= NN) v1 = false; }
  const int g = lane >> 4, c = lane & 15;
  const float hv0 = v0 ? h[s0 * 64 + lane] : 0.0f;
  const float hv1 = v1 ? h[s1 * 64 + lane] : 0.0f;
  const char* W0 = Wq + ((size_t)(v0 ? el0 : 0) << 12);
  const char* W1 = Wq + ((size_t)(v1 ? el1 : 0) << 12);
  const float* S0 = Sq + ((size_t)(v0 ? el0 : 0) << 6);
  const float* S1 = Sq + ((size_t)(v1 ? el1 : 0) << 6);
  float a0[4] = {}, a1[4] = {};
  #pragma unroll
  for (int i0 = 0; i0 < 64; i0 += 4) {
    const int i = i0 + g;
    const float hs0 = __shfl(hv0, i) * S0[i];
    const float hs1 = __shfl(hv1, i) * S1[i];
    const cx4 q0 = __builtin_nontemporal_load((const cx4*)(W0 + (i << 6) + (c << 2)));
    const cx4 q1 = __builtin_nontemporal_load((const cx4*)(W1 + (i << 6) + (c << 2)));
    a0[0] = fmaf(hs0, (float)q0[0], a0[0]);
    a0[1] = fmaf(hs0, (float)q0[1], a0[1]);
    a0[2] = fmaf(hs0, (float)q0[2], a0[2]);
    a0[3] = fmaf(hs0, (float)q0[3], a0[3]);
    a1[0] = fmaf(hs1, (float)q1[0], a1[0]);
    a1[1] = fmaf(hs1, (float)q1[1], a1[1]);
    a1[2] = fmaf(hs1, (float)q1[2], a1[2]);
    a1[3] = fmaf(hs1, (float)q1[3], a1[3]);
  }
  #pragma unroll
  for (int k = 0; k < 4; ++k) {
    a0[k] += __shfl_xor(a0[k], 16); a0[k] += __shfl_xor(a0[k], 32);
    a1[k] += __shfl_xor(a1[k], 16); a1[k] += __shfl_xor(a1[k], 32);
  }
  if (g == 0) {
    if (v0) {
      #pragma unroll
      for (int k = 0; k < 4; ++k) {
        const int o = (k << 4) + c;
        atomicAdd(agg + ((size_t)d0 << 6) + o, a0[k] + bterm[((size_t)s0 << 6) + o]);
      }
    }
    if (v1) {
      #pragma unroll
      for (int k = 0; k < 4; ++k) {
        const int o = (k << 4) + c;
        atomicAdd(agg + ((size_t)d1 << 6) + o, a1[k] + bterm[((size_t)s1 << 6) + o]);
      }
    }
  }
}

// bterm[n][o] = sum_i h[n][i] * b3[i*64+o]  (exact fp32 bias path)
__global__ __launch_bounds__(256)
void bterm_kernel(const float* __restrict__ h, const float* __restrict__ b3,
                  float* __restrict__ bt) {
  const int n = blockIdx.x * 4 + (threadIdx.x >> 6);
  if (n >= NN) return;
  const int lane = threadIdx.x & 63;
  const float hv = h[n * 64 + lane];
  float acc = 0.0f;
  #pragma unroll
  for (int i = 0; i < 64; ++i)
    acc = fmaf(__shfl(hv, i), b3[i * 64 + lane], acc);
  bt[(size_t)n * 64 + lane] = acc;
}

// wt[n*K + k] = bf16(w[k*N + n])  (transpose + cast)
__global__ void convert_t(const float* __restrict__ w, bf16_t* __restrict__ wt,
                          int K, int N) {
  int idx = blockIdx.x * 256 + threadIdx.x;
  if (idx >= K * N) return;
  int n = idx / K, k = idx - n * K;
  wt[idx] = __float2bfloat16(w[(size_t)k * N + n]);
}

__global__ void fc1_kernel(const float* __restrict__ x, const float* __restrict__ w,
                           const float* __restrict__ b, float* __restrict__ h) {
  int idx = blockIdx.x * 256 + threadIdx.x;
  if (idx >= NN * 64) return;
  int n = idx >> 6, j = idx & 63;
  h[idx] = fmaf(x[n], w[j], b[j]);
}

__global__ void deg_kernel(const int* __restrict__ ei, float* __restrict__ deg) {
  int e = blockIdx.x * 256 + threadIdx.x;
  if (e < EE) {
    unsigned d = (unsigned)ei[EE + e];
    if (d < NN) atomicAdd(&deg[d], 1.0f);
  }
}

// e1[el][0:256] = relu(attr[e0+el] @ k1_w + k1_b), zeros for rows >= ne
__global__ void k1_kernel(const float* __restrict__ attr, const float* __restrict__ w,
                          const float* __restrict__ b, bf16_t* __restrict__ e1,
                          int e0, int ne) {
  const int el = blockIdx.x;
  const int j = threadIdx.x;
  __shared__ float a[6];
  if (el < ne && j < 6) a[j] = attr[(size_t)(e0 + el) * 6 + j];
  __syncthreads();
  float v = 0.0f;
  if (el < ne) {
    v = b[j];
    #pragma unroll
    for (int i = 0; i < 6; ++i) v = fmaf(a[i], w[i * 256 + j], v);
    v = fmaxf(v, 0.0f);
  }
  e1[(size_t)el * 256 + j] = __float2bfloat16(v);
}

// h_new = relu(agg/deg + h @ root + gcn_b)
__global__ __launch_bounds__(256)
void update_kernel(const float* __restrict__ h, const float* __restrict__ agg,
                   const float* __restrict__ deg, const float* __restrict__ root,
                   const float* __restrict__ gb, float* __restrict__ hn) {
  const int n = blockIdx.x * 4 + (threadIdx.x >> 6);
  if (n >= NN) return;
  const int lane = threadIdx.x & 63;
  const float hv = h[n * 64 + lane];
  float acc = 0.0f;
  #pragma unroll
  for (int i = 0; i < 64; ++i)
    acc = fmaf(__shfl(hv, i), root[i * 64 + lane], acc);
  const float d = fmaxf(deg[n], 1.0f);
  const float v = agg[n * 64 + lane] / d + acc + gb[lane];
  hn[n * 64 + lane] = fmaxf(v, 0.0f);
}

__global__ __launch_bounds__(256)
void fc2_kernel(const float* __restrict__ h, const float* __restrict__ w,
                const float* __restrict__ b, float* __restrict__ out) {
  const int n = blockIdx.x * 4 + (threadIdx.x >> 6);
  if (n >= NN) return;
  const int lane = threadIdx.x & 63;
  float v = h[n * 64 + lane] * w[lane];
  #pragma unroll
  for (int off = 32; off > 0; off >>= 1) v += __shfl_xor(v, off);
  if (lane == 0) out[n] = v + b[0];
}

extern "C" void kernel_launch(void* const* d_in, const int* in_sizes, int n_in,
                              void* d_out, int out_size, void* d_ws, size_t ws_size,
                              hipStream_t stream) {
  const float* x     = (const float*)d_in[0];
  const int*   ei    = (const int*)d_in[1];
  const float* attr  = (const float*)d_in[2];
  const float* fc1_w = (const float*)d_in[3];
  const float* fc1_b = (const float*)d_in[4];
  const float* k1_w  = (const float*)d_in[5];
  const float* k1_b  = (const float*)d_in[6];
  const float* k2_w  = (const float*)d_in[7];
  const float* k2_b  = (const float*)d_in[8];
  const float* k3_w  = (const float*)d_in[9];
  const float* k3_b  = (const float*)d_in[10];
  const float* root  = (const float*)d_in[11];
  const float* gcn_b = (const float*)d_in[12];
  const float* fc2_w = (const float*)d_in[13];
  const float* fc2_b = (const float*)d_in[14];
  float* out = (float*)d_out;
  (void)in_sizes; (void)n_in; (void)out_size; (void)ws_size;

  char* ws = (char*)d_ws;
  size_t off = 0;
  auto take = [&](size_t bytes) -> char* {
    char* p = ws + off;
    off += (bytes + 255) & ~(size_t)255;
    return p;
  };
  // fixed buffers (~14.8 MB)
  bf16_t* k2wt  = (bf16_t*)take((size_t)512 * 256 * 2);
  bf16_t* k3wt  = (bf16_t*)take((size_t)4096 * 512 * 2);
  float*  hA    = (float*)take((size_t)NN * 64 * 4);
  float*  hB    = (float*)take((size_t)NN * 64 * 4);
  float*  agg   = (float*)take((size_t)NN * 64 * 4);
  float*  deg   = (float*)take((size_t)NN * 4);
  float*  bterm = (float*)take((size_t)NN * 64 * 4);
  // chunked fill scratch (3 chunks of 16768 edges): e1c 8.6MB + e2c 17.2MB
  const int Cc = 16768;
  bf16_t* e1c = (bf16_t*)take((size_t)Cc * 256 * 2);
  bf16_t* e2c = (bf16_t*)take((size_t)Cc * 512 * 2);
  // int8 W cache: Wq 205.5MB + Sq 12.85MB  (total ~259MB <= 256MiB ws)
  float* Sq = (float*)take((size_t)MPAD * 64 * 4);
  char*  Wq = take((size_t)MPAD * 4096);

  // weight transposes + casts
  convert_t<<<(512 * 256 + 255) / 256, 256, 0, stream>>>(k2_w, k2wt, 256, 512);
  convert_t<<<(4096 * 512 + 255) / 256, 256, 0, stream>>>(k3_w, k3wt, 512, 4096);

  // h0 = x @ fc1_w + fc1_b
  fc1_kernel<<<(NN * 64 + 255) / 256, 256, 0, stream>>>(x, fc1_w, fc1_b, hA);

  // in-degree
  hipMemsetAsync(deg, 0, NN * 4, stream);
  deg_kernel<<<(EE + 255) / 256, 256, 0, stream>>>(ei, deg);

  // fill int8 W-cache in 3 chunks: k1 -> e1c, k2 -> e2c, gemm_q -> Wq+Sq
  for (int e0 = 0; e0 < EE; e0 += Cc) {
    int ne = EE - e0; if (ne > Cc) ne = Cc;
    const int np = (ne + 127) & ~127;
    k1_kernel<<<np, 256, 0, stream>>>(attr, k1_w, k1_b, e1c, e0, ne);
    gemm_bt<true><<<(np >> 7) * 4, 256, 0, stream>>>(e1c, k2wt, k2_b, e2c, 512, 256);
    gemm_q<<<(np >> 7) * 32, 256, 0, stream>>>(e2c, k3wt, Wq, Sq, e0);
  }

  float* hc = hA;
  float* hn = hB;
  for (int l = 0; l < 3; ++l) {
    hipMemsetAsync(agg, 0, (size_t)NN * 64 * 4, stream);
    bterm_kernel<<<(NN + 3) / 4, 256, 0, stream>>>(hc, k3_b, bterm);
    msg_q<<<(EE + 7) / 8, 256, 0, stream>>>(hc, Wq, Sq, bterm, ei, agg, EE);
    update_kernel<<<(NN + 3) / 4, 256, 0, stream>>>(hc, agg, deg, root, gcn_b, hn);
    float* tmp = hc; hc = hn; hn = tmp;
  }

  fc2_kernel<<<(NN + 3) / 4, 256, 0, stream>>>(hc, fc2_w, fc2_b, out);
}